// Round 8
// baseline (785.774 us; speedup 1.0000x reference)
//
#include <hip/hip_runtime.h>

// CRF Viterbi decode (B=512, T=512, S=64).
// R16 = R15 + asm-opaque register pinning of tr[64] and the prefetch regs.
//
// R13-R15 arc: 8-wave/block design (64 CUs x 8 waves = 2 waves/SIMD, the
// TLP that should hide the readlane/cmp-cndmask stalls) keeps being defeated
// by the register allocator, which REMATERIALIZES tr[64] global loads inside
// the step loop to hit a high occupancy target. R15's waves_per_eu(2,2)
// raised VGPR 52->88 (dur 633->583) but most of tr still remats. Cost model:
// 8 waves/CU x 16 dwordx4/step = 128 KB/step/CU of L1 traffic ~ 2000 cy/step
// at ~64B/cy -> the kernel is L1-BW-bound on remat loads (obs ~2700 cy/step).
// Fix at IR level: asm volatile("" : "+v"(x)) makes each tr[k] an inline-asm
// -defined value -- the compiler CANNOT rematerialize it; with the 256-VGPR
// budget from waves_per_eu(2,2) it must keep it resident. Also pin the
// software-pipeline prefetch regs so their loads can't be sunk to use sites.
//
// Per-wave body is R10's validated code: readlane broadcast, 8 running
// argmax chains of 8 (strict >, ascending p => first-argmax, exact jnp
// semantics), left-priority merge, fmaxf keeps identical values on ties.
// Backpointers stream to global ws (coalesced, fire-and-forget; backtrace
// reads back via L2). Output: out[0..B)=path_score, out[B+b*(T-1)+t]=tag.

constexpr int Bz = 512;
constexpr int Tz = 512;
constexpr int Sz = 64;
constexpr int WPB = 8;                       // waves (= batches) per block
constexpr float NEGINF = -10000.0f;
constexpr size_t BP_DWORDS_PER_BATCH = 128 * 64;   // packed 4 steps/dword
constexpr size_t WS_NEEDED = (size_t)Bz * BP_DWORDS_PER_BATCH * 4;  // 16 MB

__device__ __forceinline__ float rlf(float x, int lane) {
    return __int_as_float(__builtin_amdgcn_readlane(__float_as_int(x), lane));
}

__device__ __forceinline__ void pin(float& x) {
    asm volatile("" : "+v"(x));              // asm-defined: no remat possible
}

// -------- R16 wide kernel: 8 waves/block, 2 waves/SIMD, bp in global --------
__global__ __launch_bounds__(WPB * 64)
__attribute__((amdgpu_waves_per_eu(2, 2)))   // 2 waves/EU target: 256 VGPR/wave
void crf_viterbi_wide(const float* __restrict__ logits,
                      const float* __restrict__ masks,
                      const float* __restrict__ trans,
                      float* __restrict__ out,
                      unsigned* __restrict__ bpg)
{
    const int n  = threadIdx.x & 63;                                  // lane id == tag id
    const int wv = __builtin_amdgcn_readfirstlane(threadIdx.x >> 6);  // uniform wave id
    const int b  = blockIdx.x * WPB + wv;                             // this wave's batch

    unsigned* __restrict__ bpw = bpg + (size_t)b * BP_DWORDS_PER_BATCH;

    __shared__ float ys[WPB][512];           // emitted tags per wave, 16 KB

    // full transitions row for this lane's tag: tr[p] = trans[n][p]
    float tr[64];
    {
        const float4* tr4 = reinterpret_cast<const float4*>(trans + (size_t)n * Sz);
        #pragma unroll
        for (int k = 0; k < 16; ++k) {
            float4 t = tr4[k];
            tr[4 * k + 0] = t.x; tr[4 * k + 1] = t.y;
            tr[4 * k + 2] = t.z; tr[4 * k + 3] = t.w;
        }
    }
    #pragma unroll
    for (int k = 0; k < 64; ++k) pin(tr[k]);  // force resident: no remat

    float fv = (n == 0) ? 0.0f : NEGINF;

    const float* lgbase = logits + (size_t)b * Tz * Sz;
    const float* mkbase = masks + (size_t)b * Tz;

    // group-of-4 software-pipelined prefetch (2 groups deep)
    float lgc[4], lgn[4], mkc[4], mkn[4];
    #pragma unroll
    for (int k = 0; k < 4; ++k) {
        lgc[k] = lgbase[(1 + k) * Sz + n];
        mkc[k] = mkbase[1 + k];
        lgn[k] = lgbase[(5 + k) * Sz + n];
        mkn[k] = mkbase[5 + k];
        pin(lgc[k]); pin(mkc[k]); pin(lgn[k]); pin(mkn[k]);
    }

    unsigned pk = 0;

    // ---- one Viterbi step (R10's validated body; literal lanes) ----
    auto step = [&](int k, float lg, float mk) -> float {
        float m[8]; int id[8];
        #pragma unroll
        for (int c = 0; c < 8; ++c) {
            m[c]  = rlf(fv, 8 * c) + tr[8 * c];
            id[c] = 8 * c;
            #pragma unroll
            for (int j = 1; j < 8; ++j) {
                const int p = 8 * c + j;
                float cand = rlf(fv, p) + tr[p];
                bool g = cand > m[c];          // uses OLD m[c]
                id[c] = g ? p : id[c];
                m[c]  = fmaxf(m[c], cand);
            }
        }
        #pragma unroll
        for (int st = 1; st < 8; st <<= 1) {
            #pragma unroll
            for (int c = 0; c < 8; c += 2 * st) {
                bool g = m[c + st] > m[c];
                id[c] = g ? id[c + st] : id[c];
                m[c]  = fmaxf(m[c], m[c + st]);
            }
        }
        pk |= ((unsigned)id[0]) << (8 * k);
        float mm = m[0];
        fv = mm + lg * mk;                     // mask multiplies emission only
        return mm;                             // pre-feat max (for path_score)
    };

    // main: groups g = 0..126 cover steps i = 4g+k (i <= 507)
    for (int g = 0; g < 127; ++g) {
        step(0, lgc[0], mkc[0]);
        step(1, lgc[1], mkc[1]);
        step(2, lgc[2], mkc[2]);
        step(3, lgc[3], mkc[3]);

        bpw[g * 64 + n] = pk;                  // coalesced 256B, fire-and-forget
        pk = 0;

        // rotate prefetch; issue loads for group g+2 (rows 4g+9 .. 4g+12)
        #pragma unroll
        for (int k = 0; k < 4; ++k) { lgc[k] = lgn[k]; mkc[k] = mkn[k]; }
        #pragma unroll
        for (int k = 0; k < 4; ++k) {
            int t = 4 * g + 9 + k;
            t = (t < Tz) ? t : (Tz - 1);
            lgn[k] = lgbase[t * Sz + n];
            mkn[k] = mkbase[t];
            pin(lgn[k]); pin(mkn[k]);          // loads stay hoisted (prefetch)
        }
    }

    // tail: steps 508, 509, 510 (group 127, k = 0..2)
    step(0, lgc[0], mkc[0]);
    step(1, lgc[1], mkc[1]);
    float psc = step(2, lgc[2], mkc[2]);
    bpw[127 * 64 + n] = pk;                    // flush steps 508..510
    if (n == 63) out[b] = psc;                 // path_score = vmaxs[-1][:,63]

    // make our own bp stores visible to our own loads
    asm volatile("s_waitcnt vmcnt(0)" ::: "memory");

    // ---- backtrace (intra-wave; R10's validated readlane chain, bp from global) ----
    unsigned wcur = bpw[127 * 64 + n];
    int w127_63 = __builtin_amdgcn_readlane((int)wcur, 63);
    int tag = (w127_63 >> 16) & 255;           // t0 = bptrs[510][63]

    for (int g = 127; g >= 0; --g) {
        unsigned wnext = (g > 0) ? bpw[(g - 1) * 64 + n] : 0u;  // prefetch (L2)
        const int smax = (g == 127) ? 2 : 3;
        for (int s = smax; s >= 0; --s) {
            int idx = 4 * g + s;
            if (n == 0) ys[wv][idx] = (float)tag;  // emit BEFORE following ptr
            int wd = __builtin_amdgcn_readlane((int)wcur, tag);  // tag is uniform
            tag = (wd >> (8 * s)) & 255;
        }
        wcur = wnext;
    }

    // same-wave LDS ordering: lane-0 writes above complete before these reads
    float* outseq = out + Bz + (size_t)b * (Tz - 1);
    for (int k = n; k < Tz - 1; k += 64) outseq[k] = ys[wv][k];
}

// ---------------- fallback: R10 kernel (validated, 356 us) ----------------
__global__ __launch_bounds__(64)
void crf_viterbi_kernel(const float* __restrict__ logits,
                        const float* __restrict__ masks,
                        const float* __restrict__ trans,
                        float* __restrict__ out)
{
    const int n = threadIdx.x;
    const int b = blockIdx.x;

    __shared__ unsigned bp[128 * 64];
    __shared__ float ys[Tz - 1];

    float tr[64];
    {
        const float4* tr4 = reinterpret_cast<const float4*>(trans + (size_t)n * Sz);
        #pragma unroll
        for (int k = 0; k < 16; ++k) {
            float4 t = tr4[k];
            tr[4 * k + 0] = t.x; tr[4 * k + 1] = t.y;
            tr[4 * k + 2] = t.z; tr[4 * k + 3] = t.w;
        }
    }

    float fv = (n == 0) ? 0.0f : NEGINF;

    const float* lgbase = logits + (size_t)b * Tz * Sz;
    const float* mkbase = masks + (size_t)b * Tz;

    float lgc[4], lgn[4], mkc[4], mkn[4];
    #pragma unroll
    for (int k = 0; k < 4; ++k) {
        lgc[k] = lgbase[(1 + k) * Sz + n];
        mkc[k] = mkbase[1 + k];
        lgn[k] = lgbase[(5 + k) * Sz + n];
        mkn[k] = mkbase[5 + k];
    }

    unsigned pk = 0;

    auto step = [&](int k, float lg, float mk) -> float {
        float m[8]; int id[8];
        #pragma unroll
        for (int c = 0; c < 8; ++c) {
            m[c]  = rlf(fv, 8 * c) + tr[8 * c];
            id[c] = 8 * c;
            #pragma unroll
            for (int j = 1; j < 8; ++j) {
                const int p = 8 * c + j;
                float cand = rlf(fv, p) + tr[p];
                bool g = cand > m[c];
                id[c] = g ? p : id[c];
                m[c]  = fmaxf(m[c], cand);
            }
        }
        #pragma unroll
        for (int st = 1; st < 8; st <<= 1) {
            #pragma unroll
            for (int c = 0; c < 8; c += 2 * st) {
                bool g = m[c + st] > m[c];
                id[c] = g ? id[c + st] : id[c];
                m[c]  = fmaxf(m[c], m[c + st]);
            }
        }
        pk |= ((unsigned)id[0]) << (8 * k);
        float mm = m[0];
        fv = mm + lg * mk;
        return mm;
    };

    for (int g = 0; g < 127; ++g) {
        step(0, lgc[0], mkc[0]);
        step(1, lgc[1], mkc[1]);
        step(2, lgc[2], mkc[2]);
        step(3, lgc[3], mkc[3]);

        bp[g * 64 + n] = pk;
        pk = 0;

        #pragma unroll
        for (int k = 0; k < 4; ++k) { lgc[k] = lgn[k]; mkc[k] = mkn[k]; }
        #pragma unroll
        for (int k = 0; k < 4; ++k) {
            int t = 4 * g + 9 + k;
            t = (t < Tz) ? t : (Tz - 1);
            lgn[k] = lgbase[t * Sz + n];
            mkn[k] = mkbase[t];
        }
    }

    step(0, lgc[0], mkc[0]);
    step(1, lgc[1], mkc[1]);
    float psc = step(2, lgc[2], mkc[2]);
    bp[127 * 64 + n] = pk;
    if (n == 63) out[b] = psc;

    unsigned wcur = bp[127 * 64 + n];
    int w127_63 = __builtin_amdgcn_readlane((int)wcur, 63);
    int tag = (w127_63 >> 16) & 255;

    for (int g = 127; g >= 0; --g) {
        unsigned wnext = (g > 0) ? bp[(g - 1) * 64 + n] : 0u;
        const int smax = (g == 127) ? 2 : 3;
        for (int s = smax; s >= 0; --s) {
            int idx = 4 * g + s;
            if (n == 0) ys[idx] = (float)tag;
            int wd = __builtin_amdgcn_readlane((int)wcur, tag);
            tag = (wd >> (8 * s)) & 255;
        }
        wcur = wnext;
    }

    __syncthreads();
    float* outseq = out + Bz + (size_t)b * (Tz - 1);
    for (int k = n; k < Tz - 1; k += 64) outseq[k] = ys[k];
}

extern "C" void kernel_launch(void* const* d_in, const int* in_sizes, int n_in,
                              void* d_out, int out_size, void* d_ws, size_t ws_size,
                              hipStream_t stream) {
    const float* logits = (const float*)d_in[0];
    const float* masks  = (const float*)d_in[1];
    const float* trans  = (const float*)d_in[2];
    float* out = (float*)d_out;
    (void)in_sizes; (void)n_in; (void)out_size;

    if (d_ws != nullptr && ws_size >= WS_NEEDED) {
        crf_viterbi_wide<<<dim3(Bz / WPB), dim3(WPB * 64), 0, stream>>>(
            logits, masks, trans, out, (unsigned*)d_ws);
    } else {
        crf_viterbi_kernel<<<dim3(Bz), dim3(64), 0, stream>>>(logits, masks, trans, out);
    }
}

// Round 9
// 416.554 us; speedup vs baseline: 1.8864x; 1.8864x over previous
//
#include <hip/hip_runtime.h>

// CRF Viterbi decode (B=512, T=512, S=64).
// R17: R9's validated 4-wave x 16-prev rendezvous structure, but TWO batches
// per block, software-pipelined across a SINGLE shared barrier per iteration:
//    phase1_A ; phase1_B ; barrier ; phase2_A ; phase2_B
// Each batch's LDS round-trip (write -> barrier -> read, ~600cy critical in
// R9) is overlapped by the OTHER batch's phase-1 issue (~190cy) and merge.
// This is program-order block placement -- no reliance on the compiler
// interleaving instructions (R11's failure) and no multi-wave-occupancy
// register fight (R13-R16's failure: allocator remats tr[] to hit 8 waves/EU
// in multi-wave blocks; here grid = 256 blocks = 1 block/CU = 4 waves/CU so
// occupancy >1/EU is unreachable and waves_per_eu(1,1) grants a 512-reg
// budget, removing the remat incentive entirely).
//
// Micro-fixes vs R9: readlanes batched into s[16] + sched_barrier(0) so the
// 16 VALU->SGPR->VALU hazards run at def-use distance >=16 instead of 1;
// tr[16] shared by both batches (same wave => same swapped tag space).
//
// Semantics identical to R9 (validated): wave w in tag space tg = n ^ 16w,
// slice prevs [16w,16w+16) at lanes 0..15 of its own fv copy (literal
// readlanes); carry-index ordered trees with strict >, left-on-tie at every
// level; merge ascending wave order => exact jnp first-argmax. Mask
// multiplies emission only. Wave 0 packs backpointers 4/dword (identity
// space) and backtraces batch A; wave 1 backtraces batch B.
// Output: out[0..B) = path_score, out[B + b*(T-1) + t] = (float)tag.

constexpr int Bz = 512;
constexpr int Tz = 512;
constexpr int Sz = 64;
constexpr int GRID = Bz / 2;           // 256 blocks, 2 batches per block
constexpr float NEGINF = -10000.0f;

__device__ __forceinline__ float rlf(float x, int lane) {
    return __int_as_float(__builtin_amdgcn_readlane(__float_as_int(x), lane));
}

// Workgroup barrier that waits only on LDS ops (lgkmcnt), NOT vmcnt:
// keeps prefetch global loads in flight across the rendezvous. (R9-validated)
__device__ __forceinline__ void lds_barrier() {
    asm volatile("s_waitcnt lgkmcnt(0)\n\ts_barrier" ::: "memory");
}

__global__ __launch_bounds__(256)
__attribute__((amdgpu_waves_per_eu(1, 1)))   // 1 block/CU by grid: free 512-reg budget
void crf_viterbi_kernel(const float* __restrict__ logits,
                        const float* __restrict__ masks,
                        const float* __restrict__ trans,
                        float* __restrict__ out)
{
    const int n  = threadIdx.x & 63;                                  // lane id
    const int w  = __builtin_amdgcn_readfirstlane(threadIdx.x >> 6);  // uniform wave id
    const int pb = 16 * w;            // first prev of this wave's slice
    const int tg = n ^ pb;            // this lane's tag in wave-w swapped space
    const int bA = blockIdx.x;        // batch A
    const int bB = blockIdx.x + GRID; // batch B

    __shared__ unsigned bpA[128 * 64];     // packed backpointers A, 32 KB
    __shared__ unsigned bpB[128 * 64];     // packed backpointers B, 32 KB
    __shared__ float pvalA[2][4][64];  __shared__ int pidxA[2][4][64];
    __shared__ float pvalB[2][4][64];  __shared__ int pidxB[2][4][64];
    __shared__ float ysA[Tz - 1];
    __shared__ float ysB[Tz - 1];

    // transitions slice (shared by both batches): tr[j] = trans[tg][pb + j]
    float tr[16];
    {
        const float4* tr4 = reinterpret_cast<const float4*>(trans + tg * 64 + pb);
        #pragma unroll
        for (int k = 0; k < 4; ++k) {
            float4 t = tr4[k];
            tr[4 * k + 0] = t.x; tr[4 * k + 1] = t.y;
            tr[4 * k + 2] = t.z; tr[4 * k + 3] = t.w;
        }
    }

    float fvA = (tg == 0) ? 0.0f : NEGINF;
    float fvB = (tg == 0) ? 0.0f : NEGINF;

    const float* lgbA = logits + (size_t)bA * Tz * Sz;
    const float* lgbB = logits + (size_t)bB * Tz * Sz;
    const float* mkbA = masks + (size_t)bA * Tz;
    const float* mkbB = masks + (size_t)bB * Tz;

    // group-of-4 software-pipelined prefetch (2 groups deep), per batch
    float lgcA[4], lgnA[4], mkcA[4], mknA[4];
    float lgcB[4], lgnB[4], mkcB[4], mknB[4];
    #pragma unroll
    for (int k = 0; k < 4; ++k) {
        lgcA[k] = lgbA[(1 + k) * Sz + tg];  mkcA[k] = mkbA[1 + k];
        lgnA[k] = lgbA[(5 + k) * Sz + tg];  mknA[k] = mkbA[5 + k];
        lgcB[k] = lgbB[(1 + k) * Sz + tg];  mkcB[k] = mkbB[1 + k];
        lgnB[k] = lgbB[(5 + k) * Sz + tg];  mknB[k] = mkbB[5 + k];
    }

    unsigned pkA = 0, pkB = 0;

    // ---- phase 1: own-slice tree, write partials (R9-validated semantics) ----
    auto phase1 = [&](int k, float fv, float (&pval)[2][4][64], int (&pidx)[2][4][64]) {
        const int buf = k & 1;
        // batched literal-lane readlanes -> SGPRs, then fenced adds:
        // def-use distance >= 16 kills the VALU->SGPR->VALU hazard stalls.
        float s[16];
        #pragma unroll
        for (int j = 0; j < 16; ++j) s[j] = rlf(fv, j);
        __builtin_amdgcn_sched_barrier(0);
        float v[16];
        #pragma unroll
        for (int j = 0; j < 16; ++j) v[j] = s[j] + tr[j];

        // carry-index ordered tree, depth 4 (strict >, left keeps ties)
        float mv[8]; int mi[8];
        #pragma unroll
        for (int c = 0; c < 8; ++c) {
            bool g = v[2 * c + 1] > v[2 * c];
            mv[c] = g ? v[2 * c + 1] : v[2 * c];
            mi[c] = g ? (2 * c + 1) : (2 * c);
        }
        #pragma unroll
        for (int st = 1; st < 8; st <<= 1) {
            #pragma unroll
            for (int c = 0; c < 8; c += 2 * st) {
                bool g = mv[c + st] > mv[c];
                mv[c] = g ? mv[c + st] : mv[c];
                mi[c] = g ? mi[c + st] : mi[c];
            }
        }
        pval[buf][w][tg] = mv[0];
        pidx[buf][w][tg] = pb + mi[0];
    };

    // ---- phase 2: merge 4 partials (ascending q, left-on-tie), update fv ----
    auto phase2 = [&](int k, float (&pval)[2][4][64], int (&pidx)[2][4][64],
                      float lg, float mk, float& fv, unsigned& pk) -> float {
        const int buf = k & 1;
        float c0 = pval[buf][0][tg], c1 = pval[buf][1][tg];
        float c2 = pval[buf][2][tg], c3 = pval[buf][3][tg];
        int   j0 = pidx[buf][0][tg], j1 = pidx[buf][1][tg];
        int   j2 = pidx[buf][2][tg], j3 = pidx[buf][3][tg];
        bool g1 = c1 > c0;  float m01 = g1 ? c1 : c0;  int k01 = g1 ? j1 : j0;
        bool g3 = c3 > c2;  float m23 = g3 ? c3 : c2;  int k23 = g3 ? j3 : j2;
        bool gm = m23 > m01;
        float m  = gm ? m23 : m01;
        int   gi = gm ? k23 : k01;
        pk |= ((unsigned)gi) << (8 * k);
        fv = m + lg * mk;                    // mask multiplies emission only
        return m;                            // pre-feat max (for path_score)
    };

    // ---- one iteration = one Viterbi step for BOTH batches, ONE barrier ----
    auto steppair = [&](int k) {
        phase1(k, fvA, pvalA, pidxA);
        phase1(k, fvB, pvalB, pidxB);        // fills A's rendezvous bubble
        lds_barrier();
        phase2(k, pvalA, pidxA, lgcA[k], mkcA[k], fvA, pkA);
        phase2(k, pvalB, pidxB, lgcB[k], mkcB[k], fvB, pkB);
    };

    // main: groups g = 0..126 cover steps i = 4g+k (i <= 507)
    for (int g = 0; g < 127; ++g) {
        steppair(0); steppair(1); steppair(2); steppair(3);

        if (w == 0) {                        // identity space: tg == n
            bpA[g * 64 + n] = pkA;
            bpB[g * 64 + n] = pkB;
        }
        pkA = 0; pkB = 0;

        // rotate prefetch; issue loads for group g+2 (rows 4g+9 .. 4g+12)
        #pragma unroll
        for (int k = 0; k < 4; ++k) {
            lgcA[k] = lgnA[k]; mkcA[k] = mknA[k];
            lgcB[k] = lgnB[k]; mkcB[k] = mknB[k];
        }
        #pragma unroll
        for (int k = 0; k < 4; ++k) {
            int t = 4 * g + 9 + k;
            t = (t < Tz) ? t : (Tz - 1);
            lgnA[k] = lgbA[t * Sz + tg];  mknA[k] = mkbA[t];
            lgnB[k] = lgbB[t * Sz + tg];  mknB[k] = mkbB[t];
        }
    }

    // tail: steps 508, 509, 510 (group 127, k = 0..2); psc from step 510
    steppair(0); steppair(1);
    phase1(2, fvA, pvalA, pidxA);
    phase1(2, fvB, pvalB, pidxB);
    lds_barrier();
    float pscA = phase2(2, pvalA, pidxA, lgcA[2], mkcA[2], fvA, pkA);
    float pscB = phase2(2, pvalB, pidxB, lgcB[2], mkcB[2], fvB, pkB);

    if (w == 0) {
        bpA[127 * 64 + n] = pkA;             // flush steps 508..510
        bpB[127 * 64 + n] = pkB;
        if (n == 63) {                       // path_score = vmaxs[-1][:,63]
            out[bA] = pscA;
            out[bB] = pscB;
        }
    }
    __syncthreads();

    // ---- backtrace: wave 0 -> batch A, wave 1 -> batch B (R9-validated) ----
    if (w == 0) {
        unsigned wcur = bpA[127 * 64 + n];
        int tag = (__builtin_amdgcn_readlane((int)wcur, 63) >> 16) & 255;
        for (int g = 127; g >= 0; --g) {
            unsigned wnext = (g > 0) ? bpA[(g - 1) * 64 + n] : 0u;
            const int smax = (g == 127) ? 2 : 3;
            for (int s = smax; s >= 0; --s) {
                int idx = 4 * g + s;
                if (n == 0) ysA[idx] = (float)tag;   // emit BEFORE following ptr
                int wd = __builtin_amdgcn_readlane((int)wcur, tag);  // tag uniform
                tag = (wd >> (8 * s)) & 255;
            }
            wcur = wnext;
        }
    } else if (w == 1) {
        unsigned wcur = bpB[127 * 64 + n];
        int tag = (__builtin_amdgcn_readlane((int)wcur, 63) >> 16) & 255;
        for (int g = 127; g >= 0; --g) {
            unsigned wnext = (g > 0) ? bpB[(g - 1) * 64 + n] : 0u;
            const int smax = (g == 127) ? 2 : 3;
            for (int s = smax; s >= 0; --s) {
                int idx = 4 * g + s;
                if (n == 0) ysB[idx] = (float)tag;
                int wd = __builtin_amdgcn_readlane((int)wcur, tag);
                tag = (wd >> (8 * s)) & 255;
            }
            wcur = wnext;
        }
    }
    __syncthreads();

    float* oA = out + Bz + (size_t)bA * (Tz - 1);
    float* oB = out + Bz + (size_t)bB * (Tz - 1);
    for (int k = threadIdx.x; k < Tz - 1; k += 256) {
        oA[k] = ysA[k];
        oB[k] = ysB[k];
    }
}

extern "C" void kernel_launch(void* const* d_in, const int* in_sizes, int n_in,
                              void* d_out, int out_size, void* d_ws, size_t ws_size,
                              hipStream_t stream) {
    const float* logits = (const float*)d_in[0];
    const float* masks  = (const float*)d_in[1];
    const float* trans  = (const float*)d_in[2];
    float* out = (float*)d_out;
    (void)in_sizes; (void)n_in; (void)out_size; (void)d_ws; (void)ws_size;

    crf_viterbi_kernel<<<dim3(GRID), dim3(256), 0, stream>>>(logits, masks, trans, out);
}